// Round 16
// baseline (95.249 us; speedup 1.0000x reference)
//
#include <hip/hip_runtime.h>
#include <math.h>

#define BATCH 8
#define CINCH 256
#define CMID  128
#define NPIX  4096   // 64*64
#define MPIX  1024   // 32*32

typedef __attribute__((ext_vector_type(8))) short bf16x8;
typedef __attribute__((ext_vector_type(4))) short s16x4;
typedef __attribute__((ext_vector_type(4))) float f32x4;

static __device__ __forceinline__ short f2bf(float f) {
    unsigned u = __float_as_uint(f);
    u = (u + 0x7fffu + ((u >> 16) & 1u)) >> 16;   // RNE bf16
    return (short)u;
}
static __device__ __forceinline__ float bf2f(short s) {
    return __uint_as_float(((unsigned)(unsigned short)s) << 16);
}

// ---------------------------------------------------------------------------
// Weight f32->bf16 pre-convert.
// theta: rows PERMUTED (dest row R holds src row perm(R)=(R&15)*8+(R>>4)),
//        scaled by log2(e). phi, g, wz: LINEAR.
// ---------------------------------------------------------------------------
__global__ __launch_bounds__(256)
void wcvt_k(const float* __restrict__ a, const float* __restrict__ b,
            const float* __restrict__ c, const float* __restrict__ d,
            short* __restrict__ o)
{
    int i = (blockIdx.x * 256 + threadIdx.x) * 4;   // 131072 total
    if (i < 32768) {   // theta: permuted rows + log2e scale
        int cr = i >> 8, col = i & 255;
        int R = (cr & 7) * 16 + (cr >> 3);   // perm(R) = cr
        float4 v = *(const float4*)(a + i);
        s16x4 rv = { f2bf(v.x * 1.44269504f), f2bf(v.y * 1.44269504f),
                     f2bf(v.z * 1.44269504f), f2bf(v.w * 1.44269504f) };
        *(s16x4*)(o + R * 256 + col) = rv;
    } else {
        const float* src; int j;
        if (i < 65536)      { src = b; j = i - 32768; }
        else if (i < 98304) { src = c; j = i - 65536; }
        else                { src = d; j = i - 98304; }
        float4 v = *(const float4*)(src + j);
        s16x4 rv = { f2bf(v.x), f2bf(v.y), f2bf(v.z), f2bf(v.w) };
        *(s16x4*)(o + i) = rv;
    }
}

// ---------------------------------------------------------------------------
// front_k: fused transpose + theta conv + maxpool + phi/g convs.
// (r12 proven 512-thread version, unchanged)
// ---------------------------------------------------------------------------
__global__ __launch_bounds__(512)
void front_k(const float* __restrict__ x,
             const short* __restrict__ th_wh, const float* __restrict__ th_b,
             const short* __restrict__ ph_wh, const float* __restrict__ ph_b,
             const short* __restrict__ g_wh,  const float* __restrict__ g_b,
             short* __restrict__ thetaO, short* __restrict__ phiO,
             short* __restrict__ gO)
{
    __shared__ float F[128 * 65];
    __shared__ short X[128 * 264];
    __shared__ short P[32 * 264];

    const int bid = blockIdx.x;
    const int t   = threadIdx.x;
    const int b   = bid & 7;
    const int r   = bid >> 3;
    const int wv  = t >> 6;
    const int l   = t & 63;
    const int lr  = l & 15;
    const int lg  = l >> 4;

    // ---- Phase A: x -> bf16 transposed tile, software-pipelined
    const int hh = wv & 1;
    const int c0 = t >> 7;
    float ra[16], rb[16];
    {
        const float* xb = x + ((size_t)(b * 256)) * 4096 + r * 128;
#pragma unroll
        for (int i = 0; i < 16; ++i)
            ra[i] = xb[(size_t)(c0 + i * 4) * 4096 + hh * 64 + l];
    }
#pragma unroll
    for (int ct = 0; ct < 4; ++ct) {
        if ((ct & 1) == 0) {
#pragma unroll
            for (int i = 0; i < 16; ++i) F[(hh * 64 + l) * 65 + c0 + i * 4] = ra[i];
            if (ct < 3) {
                const float* xb = x + ((size_t)(b * 256 + (ct + 1) * 64)) * 4096 + r * 128;
#pragma unroll
                for (int i = 0; i < 16; ++i)
                    rb[i] = xb[(size_t)(c0 + i * 4) * 4096 + hh * 64 + l];
            }
        } else {
#pragma unroll
            for (int i = 0; i < 16; ++i) F[(hh * 64 + l) * 65 + c0 + i * 4] = rb[i];
            if (ct < 3) {
                const float* xb = x + ((size_t)(b * 256 + (ct + 1) * 64)) * 4096 + r * 128;
#pragma unroll
                for (int i = 0; i < 16; ++i)
                    ra[i] = xb[(size_t)(c0 + i * 4) * 4096 + hh * 64 + l];
            }
        }
        asm volatile("s_waitcnt lgkmcnt(0)" ::: "memory");
        __builtin_amdgcn_s_barrier();
#pragma unroll
        for (int i = 0; i < 16; ++i) {
            int row = wv + i * 8;
            X[row * 264 + ct * 64 + l] = f2bf(F[row * 65 + l]);
        }
        asm volatile("s_waitcnt lgkmcnt(0)" ::: "memory");
        __builtin_amdgcn_s_barrier();
    }

    // ---- Phase B: maxpool into P
#pragma unroll
    for (int i = 0; i < 4; ++i) {
        int slot = i * 512 + t;
        int wp = slot >> 6, c4 = slot & 63;
        s16x4 v0 = *(const s16x4*)(X + (2 * wp) * 264 + c4 * 4);
        s16x4 v1 = *(const s16x4*)(X + (2 * wp + 1) * 264 + c4 * 4);
        s16x4 v2 = *(const s16x4*)(X + (64 + 2 * wp) * 264 + c4 * 4);
        s16x4 v3 = *(const s16x4*)(X + (65 + 2 * wp) * 264 + c4 * 4);
        s16x4 rm;
#pragma unroll
        for (int e = 0; e < 4; ++e) {
            float m = fmaxf(fmaxf(bf2f(v0[e]), bf2f(v1[e])),
                            fmaxf(bf2f(v2[e]), bf2f(v3[e])));
            rm[e] = f2bf(m);
        }
        *(s16x4*)(P + wp * 264 + c4 * 4) = rm;
    }
    __syncthreads();

    // ---- Phase C1: theta conv (permuted weights) -> packed bf16x8 stores
    {
        const int m0 = wv * 16;
        f32x4 o[8];
#pragma unroll
        for (int dt = 0; dt < 8; ++dt)
#pragma unroll
            for (int e = 0; e < 4; ++e) o[dt][e] = 0.f;
        for (int kt = 0; kt < 8; ++kt) {
            bf16x8 a = *(const bf16x8*)(X + (m0 + lr) * 264 + kt * 32 + lg * 8);
#pragma unroll
            for (int dt = 0; dt < 8; ++dt) {
                bf16x8 bv = *(const bf16x8*)(th_wh + (size_t)(dt * 16 + lr) * 256 + kt * 32 + lg * 8);
                o[dt] = __builtin_amdgcn_mfma_f32_16x16x32_bf16(a, bv, o[dt], 0, 0, 0);
            }
        }
        float bvt[8];
#pragma unroll
        for (int dt = 0; dt < 8; ++dt) bvt[dt] = th_b[lr * 8 + dt] * 1.44269504f;
        short* ob = thetaO + (size_t)b * NPIX * 128;
#pragma unroll
        for (int rr = 0; rr < 4; ++rr) {
            int n = r * 128 + m0 + lg * 4 + rr;
            bf16x8 sv;
#pragma unroll
            for (int dt = 0; dt < 8; ++dt) sv[dt] = f2bf(o[dt][rr] + bvt[dt]);
            *(bf16x8*)(ob + (size_t)n * 128 + lr * 8) = sv;
        }
    }

    // ---- Phase C2: phi (waves 0-3, LINEAR weights) / G (waves 4-7)
    {
        const int half = wv & 1;
        const int coH  = (wv >> 1) & 1;
        const short* wsel = ((wv < 4) ? ph_wh : g_wh) + (size_t)coH * 64 * 256;
        const float* bsel = (wv < 4) ? ph_b : g_b;

        f32x4 q[4];
#pragma unroll
        for (int dt = 0; dt < 4; ++dt)
#pragma unroll
            for (int e = 0; e < 4; ++e) q[dt][e] = 0.f;
        for (int kt = 0; kt < 8; ++kt) {
            bf16x8 a = *(const bf16x8*)(P + (half * 16 + lr) * 264 + kt * 32 + lg * 8);
#pragma unroll
            for (int dt = 0; dt < 4; ++dt) {
                bf16x8 bv = *(const bf16x8*)(wsel + (size_t)(dt * 16 + lr) * 256 + kt * 32 + lg * 8);
                q[dt] = __builtin_amdgcn_mfma_f32_16x16x32_bf16(a, bv, q[dt], 0, 0, 0);
            }
        }
        float bv4[4];
#pragma unroll
        for (int dt = 0; dt < 4; ++dt) bv4[dt] = bsel[coH * 64 + dt * 16 + lr];

        if (wv < 4) {
            short* cb = phiO + (size_t)b * 32 * 4096 + (size_t)r * 4096;
#pragma unroll
            for (int rr = 0; rr < 4; ++rr) {
                int mloc = half * 16 + lg * 4 + rr;
                short* cbb = cb + (mloc >> 4) * 512 + (mloc & 15) * 8;
#pragma unroll
                for (int dt = 0; dt < 4; ++dt) {
                    int cc = coH * 64 + dt * 16 + lr;
                    cbb[(cc >> 5) * 1024 + ((cc >> 3) & 3) * 128 + (cc & 7)]
                        = f2bf(q[dt][rr] + bv4[dt]);
                }
            }
        } else {
            short* cb = gO + (size_t)b * 32 * 4096 + (size_t)r * 4096;
            const int keyblk = half * 2 + (lg >> 1);
#pragma unroll
            for (int dt = 0; dt < 4; ++dt) {
                int cc = coH * 64 + dt * 16 + lr;
                s16x4 sv;
#pragma unroll
                for (int rr = 0; rr < 4; ++rr) sv[rr] = f2bf(q[dt][rr] + bv4[dt]);
                *(s16x4*)(cb + (size_t)((cc >> 4) * 64 + keyblk * 16 + (cc & 15)) * 8
                             + (lg & 1) * 4) = sv;
            }
        }
    }
}

// ---------------------------------------------------------------------------
// attn_fz v3: BARRIER-FREE main loop. 256 thr = 4 waves, each wave owns 32
// queries x ALL 1024 keys. phi/G read DIRECT from global — L2-resident by
// construction (2MB/batch, batch pinned to one XCD by bid&7, same mapping
// front_k wrote them with). No staging, no vmcnt, no key-split merge.
// LDS = 32KB m3 panel + 4KB P slabs = 36KB -> 2 blocks/CU.
// Tail: fused final conv, 4 waves x 64 co in 4 register-light passes.
// ---------------------------------------------------------------------------
__global__ __launch_bounds__(256, 2)
void attn_fz(const short* __restrict__ theta, const short* __restrict__ phi_sw,
             const short* __restrict__ G_sw, const short* __restrict__ wzh,
             const float* __restrict__ wzb, const float* __restrict__ x,
             float* __restrict__ out)
{
    __shared__ __align__(16) char smem[36864];  // [0:32K) m3 panel, [32K:36K) P
    const int t   = threadIdx.x;
    const int wv  = t >> 6;        // 0..3
    const int l   = t & 63;
    const int lr  = l & 15;
    const int lg  = l >> 4;
    const int bid = blockIdx.x;
    const int b   = bid & 7;       // batch -> XCD (phi/G L2-resident there)
    const int s   = bid >> 3;      // n & 31

    const short* thb = theta + (size_t)b * NPIX * 128;
    const short* phC = phi_sw + (size_t)b * 32 * 4096;   // shorts: chunk = 4096
    const short* gC  = G_sw  + (size_t)b * 32 * 4096;

    // theta B-frags: set u query n = ((wv*2+u)*16 + lr)*32 + s
    bf16x8 bq[2][4];
#pragma unroll
    for (int u = 0; u < 2; ++u) {
        int n = ((wv * 2 + u) * 16 + lr) * 32 + s;
#pragma unroll
        for (int kt = 0; kt < 4; ++kt)
            bq[u][kt] = *(const bf16x8*)(thb + (size_t)n * 128 + kt * 32 + lg * 8);
    }

    f32x4 o[2][8];
#pragma unroll
    for (int u = 0; u < 2; ++u)
#pragma unroll
        for (int dt = 0; dt < 8; ++dt)
#pragma unroll
            for (int e = 0; e < 4; ++e) o[u][dt][e] = 0.f;
    float ps_[2] = { 0.f, 0.f };

    short* pu = (short*)(smem + 32768) + wv * 512;   // wave-private P slab

    for (int c = 0; c < 32; ++c) {
        const short* pc = phC + (size_t)c * 4096;
        const short* gc = gC  + (size_t)c * 4096;

        // issue all 16 chunk loads up front (L2-hit, ~200cyc, hidden by ILP)
        bf16x8 af[8];
#pragma unroll
        for (int i = 0; i < 8; ++i)
            af[i] = *(const bf16x8*)(pc + (i * 64 + l) * 8);
        bf16x8 gf[8];
#pragma unroll
        for (int dt = 0; dt < 8; ++dt)
            gf[dt] = *(const bf16x8*)(gc + (dt * 64 + l) * 8);

        // ---- S^T = mfma(A=phi, B=theta): D[key][query col=lr]
        f32x4 ssw[2][2];
#pragma unroll
        for (int u = 0; u < 2; ++u)
#pragma unroll
            for (int mt = 0; mt < 2; ++mt)
#pragma unroll
                for (int e = 0; e < 4; ++e) ssw[u][mt][e] = 0.f;
#pragma unroll
        for (int kt = 0; kt < 4; ++kt) {
#pragma unroll
            for (int u = 0; u < 2; ++u) {
                ssw[u][0] = __builtin_amdgcn_mfma_f32_16x16x32_bf16(af[kt * 2 + 0], bq[u][kt], ssw[u][0], 0, 0, 0);
                ssw[u][1] = __builtin_amdgcn_mfma_f32_16x16x32_bf16(af[kt * 2 + 1], bq[u][kt], ssw[u][1], 0, 0, 0);
            }
        }

#pragma unroll
        for (int u = 0; u < 2; ++u) {
            // P = 2^(S2 - 40): fixed-shift softmax
#pragma unroll
            for (int mt = 0; mt < 2; ++mt) {
                s16x4 pv;
#pragma unroll
                for (int rr = 0; rr < 4; ++rr) {
                    float p = exp2f(ssw[u][mt][rr] - 40.f);
                    ps_[u] += p;
                    pv[rr] = f2bf(p);
                }
                *(s16x4*)(pu + ((mt * 2 + (lg >> 1)) * 16 + lr) * 8 + (lg & 1) * 4) = pv;
            }
            bf16x8 pa = *(const bf16x8*)(pu + l * 8);
#pragma unroll
            for (int dt = 0; dt < 8; ++dt)
                o[u][dt] = __builtin_amdgcn_mfma_f32_16x16x32_bf16(pa, gf[dt], o[u][dt], 0, 0, 0);
        }
    }

    // ---- normalize + store m3 panel (each wave owns its granule rows)
    short* m3l = (short*)smem;
#pragma unroll
    for (int u = 0; u < 2; ++u) {
        float tot = ps_[u];
        tot += __shfl_xor(tot, 16);
        tot += __shfl_xor(tot, 32);
        float inv = 1.f / tot;
        float invg[4];
#pragma unroll
        for (int rr = 0; rr < 4; ++rr) invg[rr] = __shfl(inv, lg * 4 + rr);
        const int cmb = (wv * 2 + u) * 2 + (lg >> 1);   // granule row 0..15
#pragma unroll
        for (int dt = 0; dt < 8; ++dt) {
            s16x4 zv;
#pragma unroll
            for (int rr = 0; rr < 4; ++rr) zv[rr] = f2bf(o[u][dt][rr] * invg[rr]);
            *(s16x4*)(m3l + (size_t)(cmb * 128 + dt * 16 + lr) * 8 + (lg & 1) * 4) = zv;
        }
    }
    __syncthreads();

    // ---- fused final conv: wave wv -> co [wv*64, wv*64+64) in 4 passes
#pragma unroll
    for (int nt = 0; nt < 4; ++nt) {
        const int co0 = wv * 64 + nt * 16;
        bf16x8 afr[4];
#pragma unroll
        for (int kt = 0; kt < 4; ++kt)
            afr[kt] = *(const bf16x8*)(wzh + (size_t)(co0 + lr) * 128 + kt * 32 + lg * 8);

        float xr[4][8];   // residual prefetch (issued before MFMA)
#pragma unroll
        for (int rr = 0; rr < 4; ++rr) {
            int co = co0 + lg * 4 + rr;
            const float* xb = x + ((size_t)b * 256 + co) * 4096 + s * 128;
#pragma unroll
            for (int dt = 0; dt < 8; ++dt)
                xr[rr][dt] = xb[dt * 16 + lr];
        }

        f32x4 oc[8];
#pragma unroll
        for (int dt = 0; dt < 8; ++dt)
#pragma unroll
            for (int e = 0; e < 4; ++e) oc[dt][e] = 0.f;

#pragma unroll
        for (int dt = 0; dt < 8; ++dt) {
#pragma unroll
            for (int kt = 0; kt < 4; ++kt) {
                bf16x8 bz = *(const bf16x8*)(m3l + (size_t)((kt * 4 + lg) * 128 + dt * 16 + lr) * 8);
                oc[dt] = __builtin_amdgcn_mfma_f32_16x16x32_bf16(afr[kt], bz, oc[dt], 0, 0, 0);
            }
        }

#pragma unroll
        for (int rr = 0; rr < 4; ++rr) {
            int co = co0 + lg * 4 + rr;
            float bv = wzb[co];
            float* ob = out + ((size_t)b * 256 + co) * 4096 + s * 128;
#pragma unroll
            for (int dt = 0; dt < 8; ++dt) {
                int lp = dt * 16 + lr;
                ob[lp] = oc[dt][rr] + bv + xr[rr][dt];
            }
        }
    }
}

extern "C" void kernel_launch(void* const* d_in, const int* in_sizes, int n_in,
                              void* d_out, int out_size, void* d_ws, size_t ws_size,
                              hipStream_t stream)
{
    const float* x       = (const float*)d_in[0];
    const float* theta_w = (const float*)d_in[1];
    const float* theta_b = (const float*)d_in[2];
    const float* phi_w   = (const float*)d_in[3];
    const float* phi_b   = (const float*)d_in[4];
    const float* g_w     = (const float*)d_in[5];
    const float* g_b     = (const float*)d_in[6];
    const float* wz_w    = (const float*)d_in[7];
    const float* wz_b    = (const float*)d_in[8];
    float* out = (float*)d_out;

    short* ws      = (short*)d_ws;
    short* theta_h = ws;                         // [B,4096,128]  4194304
    short* phi_h   = theta_h + (size_t)4194304;  // [B,32,4096]   1048576
    short* G_h     = phi_h + (size_t)1048576;    // [B,32,4096]   1048576
    short* wh      = G_h  + (size_t)1048576;     // 131072 bf16 weights
    short* th_wh = wh;
    short* ph_wh = wh + 32768;
    short* g_wh  = wh + 65536;
    short* wz_wh = wh + 98304;

    wcvt_k<<<dim3(128), 256, 0, stream>>>(theta_w, phi_w, g_w, wz_w, wh);

    front_k<<<dim3(256), 512, 0, stream>>>(x, th_wh, theta_b, ph_wh, phi_b,
                                           g_wh, g_b, theta_h, phi_h, G_h);

    attn_fz<<<dim3(256), 256, 0, stream>>>(theta_h, phi_h, G_h,
                                           wz_wh, wz_b, x, out);
}

// Round 18
// 73.371 us; speedup vs baseline: 1.2982x; 1.2982x over previous
//
#include <hip/hip_runtime.h>
#include <math.h>

#define BATCH 8
#define CINCH 256
#define CMID  128
#define NPIX  4096   // 64*64
#define MPIX  1024   // 32*32

typedef __attribute__((ext_vector_type(8))) short bf16x8;
typedef __attribute__((ext_vector_type(4))) short s16x4;
typedef __attribute__((ext_vector_type(4))) float f32x4;

static __device__ __forceinline__ short f2bf(float f) {
    unsigned u = __float_as_uint(f);
    u = (u + 0x7fffu + ((u >> 16) & 1u)) >> 16;   // RNE bf16
    return (short)u;
}
static __device__ __forceinline__ float bf2f(short s) {
    return __uint_as_float(((unsigned)(unsigned short)s) << 16);
}

static __device__ __forceinline__ void gl16(const void* g, void* l) {
    __builtin_amdgcn_global_load_lds(
        (const __attribute__((address_space(1))) void*)g,
        (__attribute__((address_space(3))) void*)l, 16, 0, 0);
}

// ---------------------------------------------------------------------------
// Weight f32->bf16 pre-convert.
// theta: rows PERMUTED (dest row R holds src row perm(R)=(R&15)*8+(R>>4)),
//        scaled by log2(e). phi, g, wz: LINEAR.
// ---------------------------------------------------------------------------
__global__ __launch_bounds__(256)
void wcvt_k(const float* __restrict__ a, const float* __restrict__ b,
            const float* __restrict__ c, const float* __restrict__ d,
            short* __restrict__ o)
{
    int i = (blockIdx.x * 256 + threadIdx.x) * 4;   // 131072 total
    if (i < 32768) {   // theta: permuted rows + log2e scale
        int cr = i >> 8, col = i & 255;
        int R = (cr & 7) * 16 + (cr >> 3);   // perm(R) = cr
        float4 v = *(const float4*)(a + i);
        s16x4 rv = { f2bf(v.x * 1.44269504f), f2bf(v.y * 1.44269504f),
                     f2bf(v.z * 1.44269504f), f2bf(v.w * 1.44269504f) };
        *(s16x4*)(o + R * 256 + col) = rv;
    } else {
        const float* src; int j;
        if (i < 65536)      { src = b; j = i - 32768; }
        else if (i < 98304) { src = c; j = i - 65536; }
        else                { src = d; j = i - 98304; }
        float4 v = *(const float4*)(src + j);
        s16x4 rv = { f2bf(v.x), f2bf(v.y), f2bf(v.z), f2bf(v.w) };
        *(s16x4*)(o + i) = rv;
    }
}

// ---------------------------------------------------------------------------
// front_k: fused transpose + theta conv + maxpool + phi/g convs.
// (r12 proven 512-thread version)
// ---------------------------------------------------------------------------
__global__ __launch_bounds__(512)
void front_k(const float* __restrict__ x,
             const short* __restrict__ th_wh, const float* __restrict__ th_b,
             const short* __restrict__ ph_wh, const float* __restrict__ ph_b,
             const short* __restrict__ g_wh,  const float* __restrict__ g_b,
             short* __restrict__ thetaO, short* __restrict__ phiO,
             short* __restrict__ gO)
{
    __shared__ float F[128 * 65];
    __shared__ short X[128 * 264];
    __shared__ short P[32 * 264];

    const int bid = blockIdx.x;
    const int t   = threadIdx.x;
    const int b   = bid & 7;
    const int r   = bid >> 3;
    const int wv  = t >> 6;
    const int l   = t & 63;
    const int lr  = l & 15;
    const int lg  = l >> 4;

    // ---- Phase A: x -> bf16 transposed tile, software-pipelined
    const int hh = wv & 1;
    const int c0 = t >> 7;
    float ra[16], rb[16];
    {
        const float* xb = x + ((size_t)(b * 256)) * 4096 + r * 128;
#pragma unroll
        for (int i = 0; i < 16; ++i)
            ra[i] = xb[(size_t)(c0 + i * 4) * 4096 + hh * 64 + l];
    }
#pragma unroll
    for (int ct = 0; ct < 4; ++ct) {
        if ((ct & 1) == 0) {
#pragma unroll
            for (int i = 0; i < 16; ++i) F[(hh * 64 + l) * 65 + c0 + i * 4] = ra[i];
            if (ct < 3) {
                const float* xb = x + ((size_t)(b * 256 + (ct + 1) * 64)) * 4096 + r * 128;
#pragma unroll
                for (int i = 0; i < 16; ++i)
                    rb[i] = xb[(size_t)(c0 + i * 4) * 4096 + hh * 64 + l];
            }
        } else {
#pragma unroll
            for (int i = 0; i < 16; ++i) F[(hh * 64 + l) * 65 + c0 + i * 4] = rb[i];
            if (ct < 3) {
                const float* xb = x + ((size_t)(b * 256 + (ct + 1) * 64)) * 4096 + r * 128;
#pragma unroll
                for (int i = 0; i < 16; ++i)
                    ra[i] = xb[(size_t)(c0 + i * 4) * 4096 + hh * 64 + l];
            }
        }
        asm volatile("s_waitcnt lgkmcnt(0)" ::: "memory");
        __builtin_amdgcn_s_barrier();
#pragma unroll
        for (int i = 0; i < 16; ++i) {
            int row = wv + i * 8;
            X[row * 264 + ct * 64 + l] = f2bf(F[row * 65 + l]);
        }
        asm volatile("s_waitcnt lgkmcnt(0)" ::: "memory");
        __builtin_amdgcn_s_barrier();
    }

    // ---- Phase B: maxpool into P
#pragma unroll
    for (int i = 0; i < 4; ++i) {
        int slot = i * 512 + t;
        int wp = slot >> 6, c4 = slot & 63;
        s16x4 v0 = *(const s16x4*)(X + (2 * wp) * 264 + c4 * 4);
        s16x4 v1 = *(const s16x4*)(X + (2 * wp + 1) * 264 + c4 * 4);
        s16x4 v2 = *(const s16x4*)(X + (64 + 2 * wp) * 264 + c4 * 4);
        s16x4 v3 = *(const s16x4*)(X + (65 + 2 * wp) * 264 + c4 * 4);
        s16x4 rm;
#pragma unroll
        for (int e = 0; e < 4; ++e) {
            float m = fmaxf(fmaxf(bf2f(v0[e]), bf2f(v1[e])),
                            fmaxf(bf2f(v2[e]), bf2f(v3[e])));
            rm[e] = f2bf(m);
        }
        *(s16x4*)(P + wp * 264 + c4 * 4) = rm;
    }
    __syncthreads();

    // ---- Phase C1: theta conv (permuted weights) -> packed bf16x8 stores
    {
        const int m0 = wv * 16;
        f32x4 o[8];
#pragma unroll
        for (int dt = 0; dt < 8; ++dt)
#pragma unroll
            for (int e = 0; e < 4; ++e) o[dt][e] = 0.f;
        for (int kt = 0; kt < 8; ++kt) {
            bf16x8 a = *(const bf16x8*)(X + (m0 + lr) * 264 + kt * 32 + lg * 8);
#pragma unroll
            for (int dt = 0; dt < 8; ++dt) {
                bf16x8 bv = *(const bf16x8*)(th_wh + (size_t)(dt * 16 + lr) * 256 + kt * 32 + lg * 8);
                o[dt] = __builtin_amdgcn_mfma_f32_16x16x32_bf16(a, bv, o[dt], 0, 0, 0);
            }
        }
        float bvt[8];
#pragma unroll
        for (int dt = 0; dt < 8; ++dt) bvt[dt] = th_b[lr * 8 + dt] * 1.44269504f;
        short* ob = thetaO + (size_t)b * NPIX * 128;
#pragma unroll
        for (int rr = 0; rr < 4; ++rr) {
            int n = r * 128 + m0 + lg * 4 + rr;
            bf16x8 sv;
#pragma unroll
            for (int dt = 0; dt < 8; ++dt) sv[dt] = f2bf(o[dt][rr] + bvt[dt]);
            *(bf16x8*)(ob + (size_t)n * 128 + lr * 8) = sv;
        }
    }

    // ---- Phase C2: phi (waves 0-3, LINEAR weights) / G (waves 4-7)
    {
        const int half = wv & 1;
        const int coH  = (wv >> 1) & 1;
        const short* wsel = ((wv < 4) ? ph_wh : g_wh) + (size_t)coH * 64 * 256;
        const float* bsel = (wv < 4) ? ph_b : g_b;

        f32x4 q[4];
#pragma unroll
        for (int dt = 0; dt < 4; ++dt)
#pragma unroll
            for (int e = 0; e < 4; ++e) q[dt][e] = 0.f;
        for (int kt = 0; kt < 8; ++kt) {
            bf16x8 a = *(const bf16x8*)(P + (half * 16 + lr) * 264 + kt * 32 + lg * 8);
#pragma unroll
            for (int dt = 0; dt < 4; ++dt) {
                bf16x8 bv = *(const bf16x8*)(wsel + (size_t)(dt * 16 + lr) * 256 + kt * 32 + lg * 8);
                q[dt] = __builtin_amdgcn_mfma_f32_16x16x32_bf16(a, bv, q[dt], 0, 0, 0);
            }
        }
        float bv4[4];
#pragma unroll
        for (int dt = 0; dt < 4; ++dt) bv4[dt] = bsel[coH * 64 + dt * 16 + lr];

        if (wv < 4) {
            short* cb = phiO + (size_t)b * 32 * 4096 + (size_t)r * 4096;
#pragma unroll
            for (int rr = 0; rr < 4; ++rr) {
                int mloc = half * 16 + lg * 4 + rr;
                short* cbb = cb + (mloc >> 4) * 512 + (mloc & 15) * 8;
#pragma unroll
                for (int dt = 0; dt < 4; ++dt) {
                    int cc = coH * 64 + dt * 16 + lr;
                    cbb[(cc >> 5) * 1024 + ((cc >> 3) & 3) * 128 + (cc & 7)]
                        = f2bf(q[dt][rr] + bv4[dt]);
                }
            }
        } else {
            short* cb = gO + (size_t)b * 32 * 4096 + (size_t)r * 4096;
            const int keyblk = half * 2 + (lg >> 1);
#pragma unroll
            for (int dt = 0; dt < 4; ++dt) {
                int cc = coH * 64 + dt * 16 + lr;
                s16x4 sv;
#pragma unroll
                for (int rr = 0; rr < 4; ++rr) sv[rr] = f2bf(q[dt][rr] + bv4[dt]);
                *(s16x4*)(cb + (size_t)((cc >> 4) * 64 + keyblk * 16 + (cc & 15)) * 8
                             + (lg & 1) * 4) = sv;
            }
        }
    }
}

// ---------------------------------------------------------------------------
// attn_fz (r12 best-known, byte-exact): attention + fused final conv.
// Block (b, s) computes queries n = s (mod 32) = the complete m3 panel
// [:, s*128..s*128+128), stores it to LDS in conv B-frag granule order,
// then all 8 waves run the final GEMM + bias + x residual -> out.
// P slabs: BYTE offsets smem+131072+wv*2048+u*1024 (region ends at 147456).
// ---------------------------------------------------------------------------
__global__ __launch_bounds__(512)
void attn_fz(const short* __restrict__ theta, const short* __restrict__ phi_sw,
             const short* __restrict__ G_sw, const short* __restrict__ wzh,
             const float* __restrict__ wzb, const float* __restrict__ x,
             float* __restrict__ out)
{
    __shared__ __align__(16) char smem[147456];  // 128KB stage + 16KB P slabs
    const int t   = threadIdx.x;
    const int wv  = t >> 6;
    const int l   = t & 63;
    const int lr  = l & 15;
    const int lg  = l >> 4;
    const int gid = wv >> 2;       // key-group
    const int wvl = wv & 3;        // wave-in-group
    const int bid = blockIdx.x;
    const int b   = bid & 7;       // batch -> XCD
    const int s   = bid >> 3;      // n & 31

    const short* thb = theta + (size_t)b * NPIX * 128;
    const char*  phC = (const char*)phi_sw + (size_t)b * 32 * 8192;
    const char*  gC  = (const char*)G_sw  + (size_t)b * 32 * 8192;
    const int first = gid * 16;

    auto STAGEP = [&](int bufi, int pi) {   // stage pair pi (2 chunks)
#pragma unroll
        for (int sub = 0; sub < 2; ++sub) {
            int chunk = first + pi * 2 + sub;
            const char* ps = phC + (size_t)chunk * 8192 + wvl * 2048 + l * 16;
            const char* gs = gC  + (size_t)chunk * 8192 + wvl * 2048 + l * 16;
            char* base = smem + gid * 65536 + bufi * 32768 + sub * 16384;
            gl16(ps,        base + wvl * 2048);
            gl16(ps + 1024, base + wvl * 2048 + 1024);
            gl16(gs,        base + 8192 + wvl * 2048);
            gl16(gs + 1024, base + 8192 + wvl * 2048 + 1024);
        }
    };

    STAGEP(0, 0);

    // theta B-frags: set u query n = ((wvl*2+u)*16 + lr)*32 + s
    bf16x8 bq[2][4];
#pragma unroll
    for (int u = 0; u < 2; ++u) {
        int n = ((wvl * 2 + u) * 16 + lr) * 32 + s;
#pragma unroll
        for (int kt = 0; kt < 4; ++kt)
            bq[u][kt] = *(const bf16x8*)(thb + (size_t)n * 128 + kt * 32 + lg * 8);
    }

    f32x4 o[2][8];
#pragma unroll
    for (int u = 0; u < 2; ++u)
#pragma unroll
        for (int dt = 0; dt < 8; ++dt)
#pragma unroll
            for (int e = 0; e < 4; ++e) o[u][dt][e] = 0.f;
    float ps_[2] = { 0.f, 0.f };

    for (int pi = 0; pi < 8; ++pi) {
        asm volatile("s_waitcnt vmcnt(0)" ::: "memory");
        __builtin_amdgcn_s_barrier();           // raw: stage loads below span iter
        if (pi < 7) STAGEP((pi + 1) & 1, pi + 1);

#pragma unroll
        for (int sub = 0; sub < 2; ++sub) {
            const short* pb = (const short*)(smem + gid * 65536 + (pi & 1) * 32768
                                             + sub * 16384);
            const short* gb = pb + 4096;

            // ---- S^T = mfma(A=phi, B=theta): D[key][query col=lr]
            f32x4 ssw[2][2];
#pragma unroll
            for (int u = 0; u < 2; ++u)
#pragma unroll
                for (int mt = 0; mt < 2; ++mt)
#pragma unroll
                    for (int e = 0; e < 4; ++e) ssw[u][mt][e] = 0.f;
#pragma unroll
            for (int kt = 0; kt < 4; ++kt) {
                bf16x8 a0 = *(const bf16x8*)(pb + ((kt * 2 + 0) * 64 + l) * 8);
                bf16x8 a1 = *(const bf16x8*)(pb + ((kt * 2 + 1) * 64 + l) * 8);
#pragma unroll
                for (int u = 0; u < 2; ++u) {
                    ssw[u][0] = __builtin_amdgcn_mfma_f32_16x16x32_bf16(a0, bq[u][kt], ssw[u][0], 0, 0, 0);
                    ssw[u][1] = __builtin_amdgcn_mfma_f32_16x16x32_bf16(a1, bq[u][kt], ssw[u][1], 0, 0, 0);
                }
            }

            bf16x8 gf[8];
#pragma unroll
            for (int dt = 0; dt < 8; ++dt)
                gf[dt] = *(const bf16x8*)(gb + (dt * 64 + l) * 8);

#pragma unroll
            for (int u = 0; u < 2; ++u) {
                short* pu = (short*)(smem + 131072 + wv * 2048 + u * 1024);
                // P = 2^(S2 - 40): fixed-shift softmax
#pragma unroll
                for (int mt = 0; mt < 2; ++mt) {
                    s16x4 pv;
#pragma unroll
                    for (int rr = 0; rr < 4; ++rr) {
                        float p = exp2f(ssw[u][mt][rr] - 40.f);
                        ps_[u] += p;
                        pv[rr] = f2bf(p);
                    }
                    *(s16x4*)(pu + ((mt * 2 + (lg >> 1)) * 16 + lr) * 8 + (lg & 1) * 4) = pv;
                }
                bf16x8 pa = *(const bf16x8*)(pu + l * 8);
#pragma unroll
                for (int dt = 0; dt < 8; ++dt)
                    o[u][dt] = __builtin_amdgcn_mfma_f32_16x16x32_bf16(pa, gf[dt], o[u][dt], 0, 0, 0);
            }
        }
    }

    // ---- merge partials (key-group 1 -> 0) via LDS
    __syncthreads();
    float* mg = (float*)smem;
    short* m3l = (short*)(smem + 73728);    // m3 panel [16 granule-rows][128 pix][8]
    if (wv >= 4) {
        float* mb = mg + (size_t)((wv - 4) * 64 + l) * 68;
#pragma unroll
        for (int u = 0; u < 2; ++u)
#pragma unroll
            for (int dt = 0; dt < 8; ++dt)
                *(f32x4*)(mb + (u * 8 + dt) * 4) = o[u][dt];
        mb[64] = ps_[0]; mb[65] = ps_[1];
    }
    __syncthreads();
    if (wv < 4) {
        const float* mb = mg + (size_t)(wv * 64 + l) * 68;
#pragma unroll
        for (int u = 0; u < 2; ++u)
#pragma unroll
            for (int dt = 0; dt < 8; ++dt) {
                f32x4 pv = *(const f32x4*)(mb + (u * 8 + dt) * 4);
#pragma unroll
                for (int e = 0; e < 4; ++e) o[u][dt][e] += pv[e];
            }
        ps_[0] += mb[64]; ps_[1] += mb[65];

        // normalize + store m3 panel to LDS (conv B-frag granule order)
#pragma unroll
        for (int u = 0; u < 2; ++u) {
            float tot = ps_[u];
            tot += __shfl_xor(tot, 16);
            tot += __shfl_xor(tot, 32);
            float inv = 1.f / tot;
            float invg[4];
#pragma unroll
            for (int rr = 0; rr < 4; ++rr) invg[rr] = __shfl(inv, lg * 4 + rr);
            const int cmb = (wvl * 2 + u) * 2 + (lg >> 1);   // granule row 0..15
#pragma unroll
            for (int dt = 0; dt < 8; ++dt) {
                s16x4 zv;
#pragma unroll
                for (int rr = 0; rr < 4; ++rr) zv[rr] = f2bf(o[u][dt][rr] * invg[rr]);
                *(s16x4*)(m3l + (size_t)(cmb * 128 + dt * 16 + lr) * 8 + (lg & 1) * 4) = zv;
            }
        }
    }
    __syncthreads();

    // ---- fused final conv: wave wv -> co [wv*32, wv*32+32), 128 pixels
    {
        const int co0 = wv * 32;
        bf16x8 afr[2][4];
#pragma unroll
        for (int nt = 0; nt < 2; ++nt) {
            int co = co0 + nt * 16 + lr;
#pragma unroll
            for (int kt = 0; kt < 4; ++kt)
                afr[nt][kt] = *(const bf16x8*)(wzh + (size_t)co * 128 + kt * 32 + lg * 8);
        }
        f32x4 oc[2][8];
#pragma unroll
        for (int nt = 0; nt < 2; ++nt)
#pragma unroll
            for (int dt = 0; dt < 8; ++dt)
#pragma unroll
                for (int e = 0; e < 4; ++e) oc[nt][dt][e] = 0.f;

#pragma unroll
        for (int dt = 0; dt < 8; ++dt) {
#pragma unroll
            for (int kt = 0; kt < 4; ++kt) {
                bf16x8 bz = *(const bf16x8*)(m3l + (size_t)((kt * 4 + lg) * 128 + dt * 16 + lr) * 8);
                oc[0][dt] = __builtin_amdgcn_mfma_f32_16x16x32_bf16(afr[0][kt], bz, oc[0][dt], 0, 0, 0);
                oc[1][dt] = __builtin_amdgcn_mfma_f32_16x16x32_bf16(afr[1][kt], bz, oc[1][dt], 0, 0, 0);
            }
        }

#pragma unroll
        for (int nt = 0; nt < 2; ++nt)
#pragma unroll
            for (int rr = 0; rr < 4; ++rr) {
                int co = co0 + nt * 16 + lg * 4 + rr;
                float bv = wzb[co];
                const float* xb = x + ((size_t)b * 256 + co) * 4096 + s * 128;
                float* ob = out + ((size_t)b * 256 + co) * 4096 + s * 128;
#pragma unroll
                for (int dt = 0; dt < 8; ++dt) {
                    int lp = dt * 16 + lr;
                    ob[lp] = oc[nt][dt][rr] + bv + xb[lp];
                }
            }
    }
}

extern "C" void kernel_launch(void* const* d_in, const int* in_sizes, int n_in,
                              void* d_out, int out_size, void* d_ws, size_t ws_size,
                              hipStream_t stream)
{
    const float* x       = (const float*)d_in[0];
    const float* theta_w = (const float*)d_in[1];
    const float* theta_b = (const float*)d_in[2];
    const float* phi_w   = (const float*)d_in[3];
    const float* phi_b   = (const float*)d_in[4];
    const float* g_w     = (const float*)d_in[5];
    const float* g_b     = (const float*)d_in[6];
    const float* wz_w    = (const float*)d_in[7];
    const float* wz_b    = (const float*)d_in[8];
    float* out = (float*)d_out;

    short* ws      = (short*)d_ws;
    short* theta_h = ws;                         // [B,4096,128]  4194304
    short* phi_h   = theta_h + (size_t)4194304;  // [B,32,4096]   1048576
    short* G_h     = phi_h + (size_t)1048576;    // [B,32,4096]   1048576
    short* wh      = G_h  + (size_t)1048576;     // 131072 bf16 weights
    short* th_wh = wh;
    short* ph_wh = wh + 32768;
    short* g_wh  = wh + 65536;
    short* wz_wh = wh + 98304;

    wcvt_k<<<dim3(128), 256, 0, stream>>>(theta_w, phi_w, g_w, wz_w, wh);

    front_k<<<dim3(256), 512, 0, stream>>>(x, th_wh, theta_b, ph_wh, phi_b,
                                           g_wh, g_b, theta_h, phi_h, G_h);

    attn_fz<<<dim3(256), 512, 0, stream>>>(theta_h, phi_h, G_h,
                                           wz_wh, wz_b, x, out);
}